// Round 2
// baseline (144.692 us; speedup 1.0000x reference)
//
#include <hip/hip_runtime.h>
#include <hip/hip_fp16.h>

// BackProjectionLinear: out[b,p] = sum_d apod[d] * lerp(sino[b,d], k[p,d], a[p,d]) / 63.5
// B=4, N_DET=128, N_T=2048, pixels=65536.
//
// R12b: det-major lane mapping (compile-fixed: no __builtin_amdgcn_writelane
// on this toolchain -> __shfl(t,63) + lane==j cndmask). R11's 44.8us was the
// lut stream pinned at ~1.94 TB/s: pixel-per-lane x octet blocks read 64B lut
// chunks at 1KB stride, in bursts, with HBM idle between barriers. Re-map:
// lane L owns dets {2L,2L+1}; one uint4/lane per pixel reads the pixel's full
// 1KB lut line FULLY COALESCED (single-use -> nontemporal). Sino taps come
// from a 4MB L2-resident table ws16b[det][t] = {S(t),S(t+1)} x 4 batches fp16
// (ONE aligned 16B gather per (px, det-pair) covers both taps, all batches).
// Per-pixel det-sum closes with a 6-step DPP butterfly (VALU pipe; LDS pipe
// unused). No LDS, no barriers, no atomics, no memset.
// Ceiling: max(lut 64MB coalesced ~10-12us, L2 gather ~8-14us, VALU ~5us).

#define NB      4
#define NDET    128
#define NT      2048
#define NPIX    65536
#define PXW     8                    // pixels per wave

typedef unsigned uv4 __attribute__((ext_vector_type(4)));

// ---- pass 1 (new): sino fp32[4][128][2048] -> ws16b[det][t] = uint4
//      {h2(b01@t), h2(b23@t), h2(b01@t+1), h2(b23@t+1)}  (4 MB) ----
__global__ __launch_bounds__(256)
void cvt16b(const float* __restrict__ sino, uint4* __restrict__ ws) {
    const int id = blockIdx.x * 256 + threadIdx.x;     // det*NT + t
    const int t  = id & (NT - 1);
    float c0 = sino[id];
    float c1 = sino[id +     NDET * NT];
    float c2 = sino[id + 2 * NDET * NT];
    float c3 = sino[id + 3 * NDET * NT];
    const int idn = (t < NT - 1) ? id + 1 : id;        // t=2047 entry never gathered
    float n0 = sino[idn];
    float n1 = sino[idn +     NDET * NT];
    float n2 = sino[idn + 2 * NDET * NT];
    float n3 = sino[idn + 3 * NDET * NT];
    uint4 u;
    __half2 h;
    h = __floats2half2_rn(c0, c1); u.x = *(unsigned*)&h;
    h = __floats2half2_rn(c2, c3); u.y = *(unsigned*)&h;
    h = __floats2half2_rn(n0, n1); u.z = *(unsigned*)&h;
    h = __floats2half2_rn(n2, n3); u.w = *(unsigned*)&h;
    ws[id] = u;
}

// 64-lane f32 add-reduce on the VALU pipe (classic gfx9 DPP ladder).
// Result valid in lane 63.
__device__ __forceinline__ float wave_reduce_add(float v) {
    int x;
    x = __builtin_amdgcn_update_dpp(0, __float_as_int(v), 0xB1,  0xF, 0xF, true); v += __int_as_float(x); // quad_perm [1,0,3,2]
    x = __builtin_amdgcn_update_dpp(0, __float_as_int(v), 0x4E,  0xF, 0xF, true); v += __int_as_float(x); // quad_perm [2,3,0,1]
    x = __builtin_amdgcn_update_dpp(0, __float_as_int(v), 0x141, 0xF, 0xF, true); v += __int_as_float(x); // row_half_mirror
    x = __builtin_amdgcn_update_dpp(0, __float_as_int(v), 0x140, 0xF, 0xF, true); v += __int_as_float(x); // row_mirror
    x = __builtin_amdgcn_update_dpp(0, __float_as_int(v), 0x142, 0xF, 0xF, true); v += __int_as_float(x); // row_bcast15
    x = __builtin_amdgcn_update_dpp(0, __float_as_int(v), 0x143, 0xF, 0xF, true); v += __int_as_float(x); // row_bcast31
    return v;
}

__device__ __forceinline__ void lerp_acc(unsigned kbits, unsigned abits,
                                         const uint4* __restrict__ row,
                                         float apod_d, float acc[NB]) {
    int k = (int)__uint_as_float(kbits);
    bool valid = (unsigned)k < (unsigned)(NT - 1);
    int k0 = valid ? k : 0;
    uint4 e = row[k0];                 // 16B aligned: S[k0],S[k0+1] x 4 batches
    float af = __uint_as_float(abits);
    __half2 a01 = *(__half2*)&e.x, a23 = *(__half2*)&e.y;
    __half2 b01 = *(__half2*)&e.z, b23 = *(__half2*)&e.w;
    __half2 a2  = __float2half2_rn(af);
    __half2 s01 = __hfma2(a2, __hsub2(b01, a01), a01);
    __half2 s23 = __hfma2(a2, __hsub2(b23, a23), a23);
    float w = valid ? apod_d : 0.0f;
    float2 f01 = __half22float2(s01);
    float2 f23 = __half22float2(s23);
    acc[0] = fmaf(w, f01.x, acc[0]);
    acc[1] = fmaf(w, f01.y, acc[1]);
    acc[2] = fmaf(w, f23.x, acc[2]);
    acc[3] = fmaf(w, f23.y, acc[3]);
}

// ---- pass 2 (new): det-major waves. One wave finishes PXW pixels. ----
__global__ __launch_bounds__(256, 4)
void bp_det(const uint4* __restrict__ ws,
            const float* __restrict__ lut,
            float* __restrict__ out) {
    const int tid  = threadIdx.x;
    const int lane = tid & 63;
    const int wid  = (blockIdx.x << 2) + (tid >> 6);   // global wave id
    const int px0  = wid * PXW;

    const int d0 = 2 * lane, d1 = 2 * lane + 1;
    const float C = 6.28318530717958647692f / 127.0f;
    const float apod0 = 0.5f - 0.5f * __cosf((float)d0 * C);
    const float apod1 = 0.5f - 0.5f * __cosf((float)d1 * C);

    const uint4* row0 = ws + (size_t)d0 * NT;
    const uint4* row1 = ws + (size_t)d1 * NT;
    const uv4*  lut4  = (const uv4*)lut;               // 16B = (k,a) for dets 2L,2L+1

    float res[NB] = {0.f, 0.f, 0.f, 0.f};

#pragma unroll
    for (int j = 0; j < PXW; ++j) {
        const int px = px0 + j;
        uv4 l = __builtin_nontemporal_load(lut4 + ((size_t)px * 64 + lane)); // coalesced 1KB/wave
        float acc[NB] = {0.f, 0.f, 0.f, 0.f};
        lerp_acc(l.x, l.y, row0, apod0, acc);
        lerp_acc(l.z, l.w, row1, apod1, acc);
#pragma unroll
        for (int b = 0; b < NB; ++b) {
            float t = wave_reduce_add(acc[b]);
            float t63 = __shfl(t, 63, 64);             // uniform idx -> v_readlane
            res[b] = (lane == j) ? t63 : res[b];       // v_cndmask commit
        }
    }

    const float inv_norm = 1.0f / 63.5f;               // sum(apod) == 63.5 exactly
    if (lane < PXW) {
#pragma unroll
        for (int b = 0; b < NB; ++b)
            out[(size_t)b * NPIX + px0 + lane] = res[b] * inv_norm;
    }
}

// ================= legacy R11 path (ws in [2MB,4MB)) =================
#define DBLOCK  8
#define DQ      4
#define PTILE   2048
#define THREADS 1024
#define PXPT    (PTILE / THREADS)

__global__ __launch_bounds__(256)
void cvt_kernel(const float* __restrict__ sino, uint2* __restrict__ ws16) {
    const int id = blockIdx.x * 256 + threadIdx.x;
    float v0 = sino[id];
    float v1 = sino[id + NDET * NT];
    float v2 = sino[id + 2 * NDET * NT];
    float v3 = sino[id + 3 * NDET * NT];
    __half2 h01 = __floats2half2_rn(v0, v1);
    __half2 h23 = __floats2half2_rn(v2, v3);
    uint2 u;
    u.x = *(const unsigned*)&h01;
    u.y = *(const unsigned*)&h23;
    ws16[id] = u;
}

__global__ __launch_bounds__(THREADS, 4)
void bp_kernel(const uint2* __restrict__ ws16,
               const float* __restrict__ lut,
               float* __restrict__ out) {
    __shared__ uint2 lds2[DQ * NT];

    const int tid   = threadIdx.x;
    const int octet = blockIdx.x & 15;
    const int tile  = blockIdx.x >> 4;
    const int d0    = octet * DBLOCK;
    const int px0   = tile * PTILE;

    float apod[DBLOCK];
#pragma unroll
    for (int j = 0; j < DBLOCK; ++j) {
        float x = (float)(d0 + j) * (6.28318530717958647692f / 127.0f);
        apod[j] = 0.5f - 0.5f * __cosf(x);
    }

    float acc[PXPT][NB];
#pragma unroll
    for (int i = 0; i < PXPT; ++i)
#pragma unroll
        for (int b = 0; b < NB; ++b) acc[i][b] = 0.0f;

    const float4* lp[PXPT];
#pragma unroll
    for (int i = 0; i < PXPT; ++i)
        lp[i] = (const float4*)
            (lut + ((size_t)(px0 + tid + i * THREADS) * NDET + d0) * 2);

    float4 Lcur[PXPT][2];
#pragma unroll
    for (int i = 0; i < PXPT; ++i) {
        Lcur[i][0] = lp[i][0];
        Lcur[i][1] = lp[i][1];
    }

    {
        const uint4* src = (const uint4*)(ws16 + (size_t)d0 * NT);
        uint4* dst = (uint4*)lds2;
#pragma unroll
        for (int r = 0; r < 4; ++r) dst[tid + r * THREADS] = src[tid + r * THREADS];
    }
    __syncthreads();

    float4 Lnext[PXPT][2];
#pragma unroll
    for (int i = 0; i < PXPT; ++i) {
        Lnext[i][0] = lp[i][2];
        Lnext[i][1] = lp[i][3];
    }

    auto gather = [&](const float4 (*Lq)[2], int jbase) {
#pragma unroll
        for (int i = 0; i < PXPT; ++i) {
#pragma unroll
            for (int q = 0; q < 2; ++q) {
                float4 Le = Lq[i][q];
#pragma unroll
                for (int h = 0; h < 2; ++h) {
                    float kf = h ? Le.z : Le.x;
                    float af = h ? Le.w : Le.y;
                    int   dl = q * 2 + h;
                    int k = (int)kf;
                    bool valid = (unsigned)k < (unsigned)(NT - 1);
                    float w  = valid ? apod[jbase + dl] : 0.0f;
                    int  k0  = valid ? k : 0;
                    uint2 e0 = lds2[dl * NT + k0];
                    uint2 e1 = lds2[dl * NT + k0 + 1];
                    __half2 a01 = *(__half2*)&e0.x, a23 = *(__half2*)&e0.y;
                    __half2 b01 = *(__half2*)&e1.x, b23 = *(__half2*)&e1.y;
                    __half2 a2  = __float2half2_rn(af);
                    __half2 s01 = __hfma2(a2, __hsub2(b01, a01), a01);
                    __half2 s23 = __hfma2(a2, __hsub2(b23, a23), a23);
                    float2 f01 = __half22float2(s01);
                    float2 f23 = __half22float2(s23);
                    acc[i][0] = fmaf(w, f01.x, acc[i][0]);
                    acc[i][1] = fmaf(w, f01.y, acc[i][1]);
                    acc[i][2] = fmaf(w, f23.x, acc[i][2]);
                    acc[i][3] = fmaf(w, f23.y, acc[i][3]);
                }
            }
        }
    };

    gather(Lcur, 0);
    __syncthreads();

    {
        const uint4* src = (const uint4*)(ws16 + (size_t)(d0 + DQ) * NT);
        uint4* dst = (uint4*)lds2;
#pragma unroll
        for (int r = 0; r < 4; ++r) dst[tid + r * THREADS] = src[tid + r * THREADS];
    }
    __syncthreads();

    gather(Lnext, DQ);

    const float inv_norm = 1.0f / 63.5f;
#pragma unroll
    for (int i = 0; i < PXPT; ++i) {
        const int px = px0 + tid + i * THREADS;
#pragma unroll
        for (int b = 0; b < NB; ++b) {
            atomicAdd(&out[(size_t)b * NPIX + px], acc[i][b] * inv_norm);
        }
    }
}

// ---- fallback (ws too small): fp32 staging + cvt in-kernel ----
__global__ __launch_bounds__(512, 4)
void bp_fallback(const float* __restrict__ sino,
                 const float* __restrict__ lut,
                 float* __restrict__ out) {
    __shared__ __half2 lds[4][NT];
    const int tid   = threadIdx.x;
    const int octet = blockIdx.x & 15;
    const int tile  = blockIdx.x >> 4;
    const int d0    = octet * DBLOCK;
    const int px0   = tile * 1024;
    float apod[DBLOCK];
#pragma unroll
    for (int j = 0; j < DBLOCK; ++j) {
        float x = (float)(d0 + j) * (6.28318530717958647692f / 127.0f);
        apod[j] = 0.5f - 0.5f * __cosf(x);
    }
    float4 L[2][4];
#pragma unroll
    for (int i = 0; i < 2; ++i) {
        const float4* lq = (const float4*)
            (lut + ((size_t)(px0 + tid + i * 512) * NDET + d0) * 2);
#pragma unroll
        for (int q = 0; q < 4; ++q) L[i][q] = lq[q];
    }
    float acc[2][NB];
#pragma unroll
    for (int i = 0; i < 2; ++i)
#pragma unroll
        for (int b = 0; b < NB; ++b) acc[i][b] = 0.0f;
    const float4* s4 = (const float4*)sino;
    for (int ph = 0; ph < 4; ++ph) {
        const int b0  = (ph >> 1) * 2;
        const int dh  = ph & 1;
        const int dg0 = d0 + dh * 4;
        if (ph) __syncthreads();
        for (int f = tid; f < 4 * (NT / 4); f += 512) {
            int dl = f >> 9;
            int t4 = f & 511;
            size_t row = ((size_t)b0 * NDET + dg0 + dl) * (NT / 4) + t4;
            float4 ve = s4[row];
            float4 vo = s4[row + (size_t)NDET * (NT / 4)];
            __half2* dstp = &lds[dl][t4 * 4];
            dstp[0] = __floats2half2_rn(ve.x, vo.x);
            dstp[1] = __floats2half2_rn(ve.y, vo.y);
            dstp[2] = __floats2half2_rn(ve.z, vo.z);
            dstp[3] = __floats2half2_rn(ve.w, vo.w);
        }
        __syncthreads();
#pragma unroll
        for (int i = 0; i < 2; ++i) {
#pragma unroll
            for (int q2 = 0; q2 < 2; ++q2) {
                float4 Lq = L[i][dh * 2 + q2];
#pragma unroll
                for (int h = 0; h < 2; ++h) {
                    float kf = h ? Lq.z : Lq.x;
                    float af = h ? Lq.w : Lq.y;
                    int   dl = q2 * 2 + h;
                    int k = (int)kf;
                    bool valid = (unsigned)k < (unsigned)(NT - 1);
                    float w  = valid ? apod[dh * 4 + dl] : 0.0f;
                    int  k0  = valid ? k : 0;
                    __half2 s0v = lds[dl][k0];
                    __half2 s1v = lds[dl][k0 + 1];
                    __half2 a2  = __float2half2_rn(af);
                    __half2 sk  = __hfma2(a2, __hsub2(s1v, s0v), s0v);
                    float2  fv  = __half22float2(sk);
                    acc[i][b0 + 0] = fmaf(w, fv.x, acc[i][b0 + 0]);
                    acc[i][b0 + 1] = fmaf(w, fv.y, acc[i][b0 + 1]);
                }
            }
        }
    }
    const float inv_norm = 1.0f / 63.5f;
#pragma unroll
    for (int i = 0; i < 2; ++i) {
        const int px = px0 + tid + i * 512;
#pragma unroll
        for (int b = 0; b < NB; ++b)
            atomicAdd(&out[(size_t)b * NPIX + px], acc[i][b] * inv_norm);
    }
}

extern "C" void kernel_launch(void* const* d_in, const int* in_sizes, int n_in,
                              void* d_out, int out_size, void* d_ws, size_t ws_size,
                              hipStream_t stream) {
    const float* sino = (const float*)d_in[0];
    const float* lut  = (const float*)d_in[1];
    float* out = (float*)d_out;

    const size_t ws_new = (size_t)NDET * NT * sizeof(uint4);   // 4 MB
    const size_t ws_old = (size_t)NDET * NT * sizeof(uint2);   // 2 MB

    if (ws_size >= ws_new) {
        uint4* ws = (uint4*)d_ws;
        cvt16b<<<dim3(NDET * NT / 256), dim3(256), 0, stream>>>(sino, ws);
        // 65536 px / 8 per wave = 8192 waves = 2048 blocks x 4 waves.
        // No memset: every output written exactly once (plain stores).
        bp_det<<<dim3(NPIX / PXW / 4), dim3(256), 0, stream>>>(ws, lut, out);
    } else if (ws_size >= ws_old) {
        (void)hipMemsetAsync(d_out, 0, (size_t)out_size * sizeof(float), stream);
        uint2* ws16 = (uint2*)d_ws;
        cvt_kernel<<<dim3(NDET * NT / 256), dim3(256), 0, stream>>>(sino, ws16);
        bp_kernel<<<dim3(512), dim3(THREADS), 0, stream>>>(ws16, lut, out);
    } else {
        (void)hipMemsetAsync(d_out, 0, (size_t)out_size * sizeof(float), stream);
        bp_fallback<<<dim3(1024), dim3(512), 0, stream>>>(sino, lut, out);
    }
}